// Round 2
// baseline (2185.483 us; speedup 1.0000x reference)
//
#include <hip/hip_runtime.h>
#include <math.h>

constexpr int kS  = 384;
constexpr int kS1 = 385;
constexpr int kH  = 8;
constexpr int kB  = 32;
constexpr int kD  = 256;
constexpr float kEPS = 1e-8f;
// (1/0.05) * log2(e)
constexpr float kNEG_INV_EPS_LOG2E = 28.853900817779268f;

__device__ __forceinline__ float waveReduceSum(float v) {
    #pragma unroll
    for (int m = 1; m < 64; m <<= 1) v += __shfl_xor(v, m);
    return v;
}
__device__ __forceinline__ float waveReduceMax(float v) {
    #pragma unroll
    for (int m = 1; m < 64; m <<= 1) v = fmaxf(v, __shfl_xor(v, m));
    return v;
}

// ---------------------------------------------------------------------------
// kA: tile-parallel symmetrize. grid (21 tile-pairs, 256 heads), 256 thr.
// Writes SYM (row stride 384) into the attn region; accumulates rowsums r and
// per-head max (float-as-uint atomicMax, values >= 0).
// ---------------------------------------------------------------------------
__global__ __launch_bounds__(256) void kA_sym(
    const float* __restrict__ P_, float* __restrict__ sym,
    float* __restrict__ r_ws, unsigned int* __restrict__ mxbits)
{
    const int head = blockIdx.y;
    int p = blockIdx.x, ti = 0;
    while (p >= 6 - ti) { p -= 6 - ti; ++ti; }
    const int tj = ti + p;
    const int tid = threadIdx.x;
    __shared__ float Bt[64 * 65];
    __shared__ float St[64 * 65];
    const float* P = P_ + (size_t)head * (kS1 * kS1);
    float* SYM = sym + (size_t)head * (kS1 * kS1);

    #pragma unroll
    for (int e = tid; e < 4096; e += 256) {
        int rr = e >> 6, cc = e & 63;
        Bt[rr * 65 + cc] = P[(size_t)(tj * 64 + rr + 1) * kS1 + ti * 64 + cc + 1];
    }
    __syncthreads();
    float mymax = 0.f;
    #pragma unroll
    for (int e = tid; e < 4096; e += 256) {
        int rr = e >> 6, cc = e & 63;
        float s = 0.5f * (P[(size_t)(ti * 64 + rr + 1) * kS1 + tj * 64 + cc + 1] + Bt[cc * 65 + rr]);
        St[rr * 65 + cc] = s;
        mymax = fmaxf(mymax, s);
        SYM[(size_t)(ti * 64 + rr) * kS + tj * 64 + cc] = s;
    }
    __syncthreads();
    if (ti != tj) {
        #pragma unroll
        for (int e = tid; e < 4096; e += 256) {
            int rr = e >> 6, cc = e & 63;
            SYM[(size_t)(tj * 64 + rr) * kS + ti * 64 + cc] = St[cc * 65 + rr];
        }
    }
    float wm = waveReduceMax(mymax);
    if ((tid & 63) == 0) atomicMax(mxbits + head, __float_as_uint(wm));
    if (tid < 64) {
        float s = 0.f;
        #pragma unroll 8
        for (int c = 0; c < 64; ++c) s += St[tid * 65 + c];
        atomicAdd(r_ws + head * kS + ti * 64 + tid, s);
    } else if (tid < 128 && ti != tj) {
        int c = tid - 64; float s = 0.f;
        #pragma unroll 8
        for (int rr2 = 0; rr2 < 64; ++rr2) s += St[rr2 * 65 + c];
        atomicAdd(r_ws + head * kS + tj * 64 + c, s);
    }
}

// ---------------------------------------------------------------------------
// kB: S1[i] = sum_s sym[s,i]*r[s], S2[i] = sum_s sym^2*r. grid (4 s-chunks, 256).
// ---------------------------------------------------------------------------
__global__ __launch_bounds__(384) void kB_t(
    const float* __restrict__ sym, const float* __restrict__ r_ws,
    float* __restrict__ s1acc, float* __restrict__ s2acc)
{
    const int head = blockIdx.y;
    const int s0 = blockIdx.x * 96;
    const int tid = threadIdx.x;
    __shared__ float rs[96];
    if (tid < 96) rs[tid] = r_ws[head * kS + s0 + tid];
    __syncthreads();
    const float* SYM = sym + (size_t)head * (kS1 * kS1) + (size_t)s0 * kS + tid;
    float s1 = 0.f, s2 = 0.f;
    #pragma unroll 4
    for (int k = 0; k < 96; ++k) {
        float sy = SYM[(size_t)k * kS];
        float rv = rs[k];
        s1 = fmaf(sy, rv, s1);
        s2 = fmaf(sy * sy, rv, s2);
    }
    atomicAdd(s1acc + head * kS + tid, s1);
    atomicAdd(s2acc + head * kS + tid, s2);
}

// ---------------------------------------------------------------------------
// kD: rd_acc[i,l] += sum_{s in chunk} (1 - sym*inv_mx) * Ms[s,l]. grid (4,256).
// ---------------------------------------------------------------------------
__global__ __launch_bounds__(384) void kD_stream(
    const float* __restrict__ sym, const float* __restrict__ Ms,
    const unsigned int* __restrict__ mxbits, float* __restrict__ rd_acc)
{
    const int head = blockIdx.y;
    const int s0 = blockIdx.x * 96;
    const int tid = threadIdx.x;
    __shared__ __align__(16) float MsS[96 * 16];
    ((float4*)MsS)[tid] = ((const float4*)(Ms + (size_t)head * 6144 + s0 * 16))[tid];
    __syncthreads();
    const float inv_mx = 1.0f / fmaxf(__uint_as_float(mxbits[head]), kEPS);
    const float* SYM = sym + (size_t)head * (kS1 * kS1) + (size_t)s0 * kS + tid;
    float rd[16];
    #pragma unroll
    for (int l = 0; l < 16; ++l) rd[l] = 0.f;
    const float4* Ms4 = (const float4*)MsS;
    #pragma unroll 2
    for (int k = 0; k < 96; ++k) {
        float dp = fmaf(-inv_mx, SYM[(size_t)k * kS], 1.0f);
        float4 m0 = Ms4[k * 4 + 0];
        float4 m1 = Ms4[k * 4 + 1];
        float4 m2 = Ms4[k * 4 + 2];
        float4 m3 = Ms4[k * 4 + 3];
        rd[0]  = fmaf(dp, m0.x, rd[0]);  rd[1]  = fmaf(dp, m0.y, rd[1]);
        rd[2]  = fmaf(dp, m0.z, rd[2]);  rd[3]  = fmaf(dp, m0.w, rd[3]);
        rd[4]  = fmaf(dp, m1.x, rd[4]);  rd[5]  = fmaf(dp, m1.y, rd[5]);
        rd[6]  = fmaf(dp, m1.z, rd[6]);  rd[7]  = fmaf(dp, m1.w, rd[7]);
        rd[8]  = fmaf(dp, m2.x, rd[8]);  rd[9]  = fmaf(dp, m2.y, rd[9]);
        rd[10] = fmaf(dp, m2.z, rd[10]); rd[11] = fmaf(dp, m2.w, rd[11]);
        rd[12] = fmaf(dp, m3.x, rd[12]); rd[13] = fmaf(dp, m3.y, rd[13]);
        rd[14] = fmaf(dp, m3.z, rd[14]); rd[15] = fmaf(dp, m3.w, rd[15]);
    }
    float* dst = rd_acc + (size_t)head * 6144 + tid * 16;
    #pragma unroll
    for (int l = 0; l < 16; ++l) atomicAdd(dst + l, rd[l]);
}

// ---------------------------------------------------------------------------
// kSolve: per-head tens -> K -> Sinkhorn(20). mode 0: closed-form iter-1 from
// S1/S2 (writes a, cc1, Ms). mode 1: tens from rd_acc, write Ms, zero rd_acc.
// mode 2: final -> alpha.
// ---------------------------------------------------------------------------
__global__ __launch_bounds__(384) void kSolve(
    const float* __restrict__ DG, const float* __restrict__ bmarg,
    float* __restrict__ a_ws, const unsigned int* __restrict__ mxbits,
    float* __restrict__ cc1_ws, const float* __restrict__ s2acc,
    float* __restrict__ rd_acc, float* __restrict__ Ms,
    float* __restrict__ alpha_out, int mode)
{
    const int head = blockIdx.x;
    const int tid  = threadIdx.x;
    const int lane = tid & 63, wid = tid >> 6;
    __shared__ float Ks[kS * 17];
    __shared__ float ravu[kS];
    __shared__ float part[16 * 24];
    __shared__ float C2l[256];
    __shared__ float bl16[16], cb16[16], cC216[16], vls[16], wred[6];

    if (tid < 256) C2l[tid] = DG[head * 256 + tid];
    if (tid >= 256 && tid < 272) bl16[tid - 256] = bmarg[head * 16 + (tid - 256)];
    __syncthreads();
    if (tid < 16) {
        float cb = 0.f, cc2 = 0.f;
        #pragma unroll
        for (int k = 0; k < 16; ++k) {
            cb += bl16[k] * C2l[tid * 16 + k];
            float c2 = C2l[k * 16 + tid];
            cc2 = fmaf(bl16[k] * c2, c2, cc2);
        }
        cb16[tid] = cb; cC216[tid] = cc2;
    }

    float a_i, cc1, u_i = 0.f;
    float tens16[16];

    if (mode == 0) {
        float r_i = a_ws[head * kS + tid];
        float tw = waveReduceSum(r_i);
        if (lane == 0) wred[wid] = tw;
        __syncthreads();
        const float total = wred[0] + wred[1] + wred[2] + wred[3] + wred[4] + wred[5];
        const float inv_mx = 1.0f / fmaxf(__uint_as_float(mxbits[head]), kEPS);
        const float den_a = fmaxf(total * inv_mx, kEPS);
        a_i = (r_i * inv_mx) / den_a;
        a_ws[head * kS + tid] = a_i;
        const float S1 = cc1_ws[head * kS + tid];
        const float S2 = s2acc[head * kS + tid];
        const float sc = inv_mx / den_a;
        const float t1 = (total - inv_mx * S1) * sc;
        cc1 = fmaf(inv_mx * inv_mx, S2, fmaf(-2.0f * inv_mx, S1, total)) * sc;
        cc1_ws[head * kS + tid] = cc1;
        #pragma unroll
        for (int l = 0; l < 16; ++l)
            tens16[l] = cc1 + cC216[l] - 2.0f * cb16[l] * t1;
    } else {
        a_i = a_ws[head * kS + tid];
        cc1 = cc1_ws[head * kS + tid];
        float4* rp = (float4*)(rd_acc + (size_t)head * 6144 + tid * 16);
        float4 rd0 = rp[0], rd1 = rp[1], rd2 = rp[2], rd3 = rp[3];
        if (mode == 1) {
            float4 z = make_float4(0.f, 0.f, 0.f, 0.f);
            rp[0] = z; rp[1] = z; rp[2] = z; rp[3] = z;
        }
        __syncthreads();   // cC216 ready
        tens16[0]  = cc1 + cC216[0]  - 2.f * rd0.x; tens16[1]  = cc1 + cC216[1]  - 2.f * rd0.y;
        tens16[2]  = cc1 + cC216[2]  - 2.f * rd0.z; tens16[3]  = cc1 + cC216[3]  - 2.f * rd0.w;
        tens16[4]  = cc1 + cC216[4]  - 2.f * rd1.x; tens16[5]  = cc1 + cC216[5]  - 2.f * rd1.y;
        tens16[6]  = cc1 + cC216[6]  - 2.f * rd1.z; tens16[7]  = cc1 + cC216[7]  - 2.f * rd1.w;
        tens16[8]  = cc1 + cC216[8]  - 2.f * rd2.x; tens16[9]  = cc1 + cC216[9]  - 2.f * rd2.y;
        tens16[10] = cc1 + cC216[10] - 2.f * rd2.z; tens16[11] = cc1 + cC216[11] - 2.f * rd2.w;
        tens16[12] = cc1 + cC216[12] - 2.f * rd3.x; tens16[13] = cc1 + cC216[13] - 2.f * rd3.y;
        tens16[14] = cc1 + cC216[14] - 2.f * rd3.z; tens16[15] = cc1 + cC216[15] - 2.f * rd3.w;
    }

    #pragma unroll
    for (int l = 0; l < 16; ++l)
        Ks[tid * 17 + l] = exp2f(tens16[l] * (-kNEG_INV_EPS_LOG2E));
    __syncthreads();

    float vreg[16];
    #pragma unroll
    for (int l = 0; l < 16; ++l) vreg[l] = 1.0f;
    for (int it = 0; it < 20; ++it) {
        float su = 0.f;
        #pragma unroll
        for (int l = 0; l < 16; ++l) su = fmaf(Ks[tid * 17 + l], vreg[l], su);
        u_i = a_i / fmaxf(su, 1e-30f);
        ravu[tid] = u_i;
        __syncthreads();
        {
            int l = tid & 15, g = tid >> 4;
            float sv = 0.f;
            #pragma unroll
            for (int j = 0; j < 16; ++j)
                sv = fmaf(Ks[(g * 16 + j) * 17 + l], ravu[g * 16 + j], sv);
            part[l * 24 + g] = sv;
        }
        __syncthreads();
        if (tid < 16) {
            float dn = 0.f;
            #pragma unroll
            for (int g = 0; g < 24; ++g) dn += part[tid * 24 + g];
            vls[tid] = bl16[tid] / fmaxf(dn, 1e-30f);
        }
        __syncthreads();
        #pragma unroll
        for (int l = 0; l < 16; ++l) vreg[l] = vls[l];
    }

    if (mode <= 1) {
        float wk[16];
        #pragma unroll
        for (int k = 0; k < 16; ++k) wk[k] = Ks[tid * 17 + k] * vreg[k];
        float m[16];
        #pragma unroll
        for (int l = 0; l < 16; ++l) {
            float acc = 0.f;
            #pragma unroll
            for (int k = 0; k < 16; ++k) acc = fmaf(wk[k], C2l[l * 16 + k], acc);
            m[l] = acc * u_i;
        }
        float4* Ms4 = (float4*)(Ms + (size_t)head * 6144 + tid * 16);
        Ms4[0] = make_float4(m[0],  m[1],  m[2],  m[3]);
        Ms4[1] = make_float4(m[4],  m[5],  m[6],  m[7]);
        Ms4[2] = make_float4(m[8],  m[9],  m[10], m[11]);
        Ms4[3] = make_float4(m[12], m[13], m[14], m[15]);
    } else {
        float g = 0.f;
        #pragma unroll
        for (int l = 0; l < 16; ++l)
            g = fmaf(tens16[l] * Ks[tid * 17 + l], vreg[l], g);
        g *= u_i;
        float gww = waveReduceSum(g);
        __syncthreads();
        if (lane == 0) wred[wid] = gww;
        __syncthreads();
        if (tid == 0)
            alpha_out[head] = expf(-(wred[0] + wred[1] + wred[2] + wred[3] + wred[4] + wred[5]));
    }
}

// ---------------------------------------------------------------------------
// K2: sharpen prior_Q by alpha, build masked row-normalized attn.
// ---------------------------------------------------------------------------
__global__ __launch_bounds__(256) void k2_attn(
    const float* __restrict__ priorQ,
    const float* __restrict__ alpha_in,
    float* __restrict__ attn_out)
{
    const int tid  = threadIdx.x;
    const int lane = tid & 63, wid = tid >> 6;
    const int head = blockIdx.x / 97;
    const int i    = (blockIdx.x % 97) * 4 + wid;
    if (i >= kS1) return;
    float* row = attn_out + (size_t)head * (kS1 * kS1) + (size_t)i * kS1;
    if (i == 0) {
        const float val = 1.0f / 384.0f;
        for (int j = lane; j < kS1; j += 64) row[j] = (j == 0) ? 0.f : val;
        return;
    }
    const float e = 1.0f + alpha_in[head];
    const float* q = priorQ + (size_t)head * (kS * kS) + (size_t)(i - 1) * kS;
    float p[6];
    float loc = 0.f, locd = 0.f;
    #pragma unroll
    for (int k = 0; k < 6; ++k) {
        int j = lane + k * 64;
        float qv = fmaxf(q[j], kEPS);
        float pv = exp2f(e * log2f(qv));
        p[k] = pv;
        loc += pv;
        if (j == i - 1) locd = pv;
    }
    float sum = loc, pd = locd;
    #pragma unroll
    for (int m = 1; m < 64; m <<= 1) { sum += __shfl_xor(sum, m); pd += __shfl_xor(pd, m); }
    const float qsum  = fmaxf(sum, kEPS);
    const float srow  = (sum - pd) / qsum;
    const float scale = 1.0f / (qsum * fmaxf(srow, kEPS));
    if (lane == 0) row[0] = 0.f;
    #pragma unroll
    for (int k = 0; k < 6; ++k) {
        int j = lane + k * 64;
        row[1 + j] = (j == i - 1) ? 0.f : p[k] * scale;
    }
}

// ---------------------------------------------------------------------------
// K3: vfull = nv @ v_w^T + v_b
// ---------------------------------------------------------------------------
__global__ __launch_bounds__(256) void k3_vproj(
    const float* __restrict__ nv, const float* __restrict__ vw,
    const float* __restrict__ vb, float* __restrict__ vfull)
{
    __shared__ float At[64][17];
    __shared__ float Bt[256][17];
    const int tid = threadIdx.x;
    const int r0  = blockIdx.x * 64;
    const int tx  = tid & 31;
    const int ty  = tid >> 5;
    const int M   = kB * kS1;
    float acc[8][8];
    #pragma unroll
    for (int ri = 0; ri < 8; ++ri)
        #pragma unroll
        for (int ci = 0; ci < 8; ++ci) acc[ri][ci] = 0.f;

    for (int k0 = 0; k0 < 256; k0 += 16) {
        __syncthreads();
        for (int e = tid; e < 1024; e += 256) {
            int r = e >> 4, kk = e & 15;
            int rowi = r0 + r;
            At[r][kk] = (rowi < M) ? nv[rowi * 256 + k0 + kk] : 0.f;
        }
        for (int e = tid; e < 4096; e += 256) {
            int c = e >> 4, kk = e & 15;
            Bt[c][kk] = vw[c * 256 + k0 + kk];
        }
        __syncthreads();
        #pragma unroll
        for (int kk = 0; kk < 16; ++kk) {
            float av[8], bv[8];
            #pragma unroll
            for (int ri = 0; ri < 8; ++ri) av[ri] = At[ty * 8 + ri][kk];
            #pragma unroll
            for (int ci = 0; ci < 8; ++ci) bv[ci] = Bt[tx + 32 * ci][kk];
            #pragma unroll
            for (int ri = 0; ri < 8; ++ri)
                #pragma unroll
                for (int ci = 0; ci < 8; ++ci)
                    acc[ri][ci] = fmaf(av[ri], bv[ci], acc[ri][ci]);
        }
    }
    for (int ri = 0; ri < 8; ++ri) {
        int rowi = r0 + ty * 8 + ri;
        if (rowi < M) {
            #pragma unroll
            for (int ci = 0; ci < 8; ++ci) {
                int c = tx + 32 * ci;
                vfull[rowi * 256 + c] = acc[ri][ci] + vb[c];
            }
        }
    }
}

// ---------------------------------------------------------------------------
// K4: basis = attn @ vfull (per b,h slice). 4i x 4c register tile.
// grid (4 i-tiles, 8 heads, 32 batch), 256 thr.
// ---------------------------------------------------------------------------
__global__ __launch_bounds__(256) void k4_ctx(
    const float* __restrict__ attn, const float* __restrict__ vfull,
    float* __restrict__ basis)
{
    const int tid = threadIdx.x;
    const int it0 = blockIdx.x * 128;
    const int h   = blockIdx.y;
    const int bb  = blockIdx.z;
    __shared__ __align__(16) float at[16][132];
    __shared__ __align__(16) float vs[16][36];
    const float* A = attn + (size_t)(bb * kH + h) * (kS1 * kS1);
    const float* V = vfull + (size_t)bb * kS1 * 256 + h * 32;
    const int itr = tid >> 3;   // 0..31 (4 rows each)
    const int ct  = tid & 7;    // 0..7  (4 cols each)
    float4 acc0 = make_float4(0, 0, 0, 0), acc1 = acc0, acc2 = acc0, acc3 = acc0;

    for (int j0 = 0; j0 < kS1; j0 += 16) {
        __syncthreads();
        #pragma unroll
        for (int e = tid; e < 2048; e += 256) {
            int jj = e & 15, ii = e >> 4;
            int gi = it0 + ii, gj = j0 + jj;
            at[jj][ii] = (gi < kS1 && gj < kS1) ? A[(size_t)gi * kS1 + gj] : 0.f;
        }
        #pragma unroll
        for (int e = tid; e < 512; e += 256) {
            int cc = e & 31, jj = e >> 5;
            int gj = j0 + jj;
            vs[jj][cc] = (gj < kS1) ? V[(size_t)gj * 256 + cc] : 0.f;
        }
        __syncthreads();
        #pragma unroll
        for (int jj = 0; jj < 16; ++jj) {
            float4 vv = *(const float4*)&vs[jj][ct * 4];
            float4 aa = *(const float4*)&at[jj][itr * 4];
            acc0.x = fmaf(aa.x, vv.x, acc0.x); acc0.y = fmaf(aa.x, vv.y, acc0.y);
            acc0.z = fmaf(aa.x, vv.z, acc0.z); acc0.w = fmaf(aa.x, vv.w, acc0.w);
            acc1.x = fmaf(aa.y, vv.x, acc1.x); acc1.y = fmaf(aa.y, vv.y, acc1.y);
            acc1.z = fmaf(aa.y, vv.z, acc1.z); acc1.w = fmaf(aa.y, vv.w, acc1.w);
            acc2.x = fmaf(aa.z, vv.x, acc2.x); acc2.y = fmaf(aa.z, vv.y, acc2.y);
            acc2.z = fmaf(aa.z, vv.z, acc2.z); acc2.w = fmaf(aa.z, vv.w, acc2.w);
            acc3.x = fmaf(aa.w, vv.x, acc3.x); acc3.y = fmaf(aa.w, vv.y, acc3.y);
            acc3.z = fmaf(aa.w, vv.z, acc3.z); acc3.w = fmaf(aa.w, vv.w, acc3.w);
        }
    }
    float4 accs[4] = {acc0, acc1, acc2, acc3};
    #pragma unroll
    for (int r = 0; r < 4; ++r) {
        int gi = it0 + itr * 4 + r;
        if (gi < kS1)
            *(float4*)&basis[((size_t)bb * kS1 + gi) * 256 + h * 32 + ct * 4] = accs[r];
    }
}

extern "C" void kernel_launch(void* const* d_in, const int* in_sizes, int n_in,
                              void* d_out, int out_size, void* d_ws, size_t ws_size,
                              hipStream_t stream) {
    (void)in_sizes; (void)n_in; (void)out_size; (void)ws_size;
    const float* nv    = (const float*)d_in[1];
    const float* sattn = (const float*)d_in[2];
    const float* pq    = (const float*)d_in[3];
    const float* dg    = (const float*)d_in[4];
    const float* bm    = (const float*)d_in[5];
    const float* vw    = (const float*)d_in[6];
    const float* vb    = (const float*)d_in[7];

    float* out   = (float*)d_out;
    float* basis = out;                                   // 32*385*256 floats
    float* attnO = out + (size_t)kB * kS1 * kD;           // 256 heads * 148225 (SYM scratch)

    // GW smalls live in the basis region (fully overwritten by k4 at the end)
    float*        r_ws   = basis;                         // 256*384
    unsigned int* mxbits = (unsigned int*)(basis + 98304);// 256
    float*        s1acc  = basis + 98560;                 // 256*384 (becomes cc1)
    float*        s2acc  = basis + 196864;                // 256*384
    float*        alpha  = basis + 295168;                // 256

    // rd_acc + Ms live in ws; overwritten by vfull after the GW phase
    float* rd_acc = (float*)d_ws;                         // 256*384*16
    float* Ms     = rd_acc + 1572864;                     // 256*384*16
    float* vfull  = (float*)d_ws;                         // 12320*256 (after GW)

    hipMemsetAsync(basis, 0, 295424 * 4, stream);         // r, mx, S1, S2, alpha
    hipMemsetAsync(rd_acc, 0, 6291456, stream);           // rd_acc

    kA_sym<<<dim3(21, 256), 256, 0, stream>>>(sattn, attnO, r_ws, mxbits);
    kB_t<<<dim3(4, 256), 384, 0, stream>>>(attnO, r_ws, s1acc, s2acc);
    kSolve<<<256, 384, 0, stream>>>(dg, bm, r_ws, mxbits, s1acc, s2acc, rd_acc, Ms, alpha, 0);
    for (int it = 1; it <= 4; ++it) {
        kD_stream<<<dim3(4, 256), 384, 0, stream>>>(attnO, Ms, mxbits, rd_acc);
        kSolve<<<256, 384, 0, stream>>>(dg, bm, r_ws, mxbits, s1acc, s2acc, rd_acc, Ms, alpha,
                                        it < 4 ? 1 : 2);
    }
    k2_attn<<<256 * 97, 256, 0, stream>>>(pq, alpha, attnO);
    k3_vproj<<<193, 256, 0, stream>>>(nv, vw, vb, vfull);
    k4_ctx<<<dim3(4, 8, 32), 256, 0, stream>>>(attnO, vfull, basis);
}